// Round 10
// baseline (590.213 us; speedup 1.0000x reference)
//
#include <hip/hip_runtime.h>
#include <hip/hip_bf16.h>
#include <cstdint>
#include <cstddef>

#define B_   128
#define NCH  64
#define T_   30720
#define EPSF 1e-12f
#define THRF 0.5f

typedef float  f32x4 __attribute__((ext_vector_type(4)));
typedef short  s16x8 __attribute__((ext_vector_type(8)));
typedef unsigned short u16;

#define AS1 __attribute__((address_space(1)))
#define AS3 __attribute__((address_space(3)))

static __device__ __forceinline__ short bf16s(float f) {
    return (short)__builtin_bit_cast(u16, __float2bfloat16(f));
}

// ---------------------------------------------------------------------------
// Stage 1: wave-private, barrier-free DMA pipeline.
// Block = 4 waves; wave w owns t-range [w*Tc/4, (w+1)*Tc/4) of its chunk and
// a PRIVATE LDS region lds[w][2][64ch x 32t] (8 KB x 2). Per 32-t K-step s:
//   1. (end of prev iter) DMA(s+1): 8x global_load_lds dwordx4 into its own
//      buffer -- no other wave ever touches it -> NO barriers in the loop.
//   2. counted per-wave wait: in-order VMEM queue [.., DMA(s), ST(s-1)(8),
//      DMA(s+1)(8)] -> vmcnt(16) guarantees DMA(s) landed, stores still fly.
//   3. 8x ds_read_b128 (granule-XOR swizzle, conflict-free) = the whole 8 KB
//      once; NT-store the same regs to out_x (fused copy, exactly-once),
//      fp32 csums, cvt->bf16 ONCE (was 4x redundant across waves in R8),
//      16 MFMA into full 64x64 acc (symmetric -> transpose-immune).
// Waves free-run & self-stagger -> continuous CU read stream (vs R8's
// barrier-quantized 32 KB bursts). 8 KB x 8 waves = 64 KB reads in flight
// per CU >> ~25 KB BW*latency product.
// Epilogue (once): stash 4 partial Grams in the reused 64 KB LDS, single
// __syncthreads, merge -> P. Per-wave S partials -> workspace (stage2 sums).
// bf16 Gram: corr err ~4e-3 << 0.108 threshold (verified absmax 0 since R3).
// ---------------------------------------------------------------------------
__global__ __launch_bounds__(256) void corr_stage1(
    const float* __restrict__ x, float* __restrict__ out_x,
    float* __restrict__ P, float* __restrict__ S,
    int split, int Tc)
{
    __shared__ __align__(16) float lds[4][2][NCH * 32];   // 64 KB exactly

    const int tid  = threadIdx.x;
    const int lane = tid & 63;
    const int w    = tid >> 6;          // wave 0..3

    const int bid = blockIdx.x;
    const int b   = bid / split;
    const int c   = bid - b * split;

    const int tw0 = w * (Tc >> 2);      // wave's private t-offset
    const size_t base = (size_t)b * ((size_t)NCH * T_) + (size_t)c * Tc + tw0;
    const float* xw = x + base;
    float*       ow = out_x + base;

    const int NK = Tc >> 7;             // 32-t K-steps per wave (=60)

    // DMA mapping: instr kk covers rows kk*8..kk*8+7 (8 rows x 8 granules of
    // 16 B). lane -> row = kk*8 + (lane>>3), granule = lane&7. Source granule
    // pre-swizzled by row&7 (= lane>>3) so LDS dest stays lane-linear.
    const int gsw = (lane & 7) ^ (lane >> 3);
    const size_t srcBase = (size_t)(lane >> 3) * T_ + (size_t)(gsw * 4);

    // fragment mapping (16x16x32): fr = matrix row in block, g8 = k-subgroup
    const int fr = lane & 15;
    const int g8 = lane >> 4;
    // tile-local ds offsets (floats), s-independent: row = rb*16+fr,
    // granules (2g8, 2g8+1) ^ (fr&7)
    int offL[4], offH[4];
    #pragma unroll
    for (int rb = 0; rb < 4; ++rb) {
        offL[rb] = rb * 512 + fr * 32 + (((2 * g8)     ^ (fr & 7)) << 2);
        offH[rb] = rb * 512 + fr * 32 + (((2 * g8 + 1) ^ (fr & 7)) << 2);
    }

    f32x4 acc[4][4];
    #pragma unroll
    for (int rb = 0; rb < 4; ++rb)
        #pragma unroll
        for (int cb = 0; cb < 4; ++cb) acc[rb][cb] = (f32x4)(0.f);
    float csum[4] = {0.f, 0.f, 0.f, 0.f};

    auto dma = [&](int s, int buf) {
        #pragma unroll
        for (int kk = 0; kk < 8; ++kk) {
            const float* src = xw + srcBase + (size_t)kk * (8 * T_) + (size_t)(s * 32);
            float* dst = &lds[w][buf][kk * 256];   // wave-uniform, lane-linear
            __builtin_amdgcn_global_load_lds((const AS1 void*)src,
                                             (AS3 void*)dst, 16, 0, 0);
        }
    };

    dma(0, 0);
    dma(1, 1);

    for (int s = 0; s < NK; ++s) {
        // counted per-wave wait: DMA(s) retired; allowed outstanding =
        // (s>0 ? ST(s-1)=8 : 0) + (s+1<NK ? DMA(s+1)=8 : 0)
        if (s == 0 || s == NK - 1) {
            asm volatile("s_waitcnt vmcnt(8)" ::: "memory");
        } else {
            asm volatile("s_waitcnt vmcnt(16)" ::: "memory");
        }
        __builtin_amdgcn_sched_barrier(0);

        const float* Lw = lds[w][s & 1];
        f32x4 lo[4], hi[4];
        #pragma unroll
        for (int rb = 0; rb < 4; ++rb) {
            lo[rb] = *reinterpret_cast<const f32x4*>(&Lw[offL[rb]]);
            hi[rb] = *reinterpret_cast<const f32x4*>(&Lw[offH[rb]]);
        }

        s16x8 A[4];
        #pragma unroll
        for (int rb = 0; rb < 4; ++rb) {
            float* q = ow + (size_t)(rb * 16 + fr) * T_ + (size_t)(s * 32 + g8 * 8);
            __builtin_nontemporal_store(lo[rb], reinterpret_cast<f32x4*>(q));
            __builtin_nontemporal_store(hi[rb], reinterpret_cast<f32x4*>(q + 4));
            csum[rb] += ((lo[rb].x + lo[rb].y) + (lo[rb].z + lo[rb].w))
                      + ((hi[rb].x + hi[rb].y) + (hi[rb].z + hi[rb].w));
            A[rb][0] = bf16s(lo[rb].x); A[rb][1] = bf16s(lo[rb].y);
            A[rb][2] = bf16s(lo[rb].z); A[rb][3] = bf16s(lo[rb].w);
            A[rb][4] = bf16s(hi[rb].x); A[rb][5] = bf16s(hi[rb].y);
            A[rb][6] = bf16s(hi[rb].z); A[rb][7] = bf16s(hi[rb].w);
        }

        #pragma unroll
        for (int rb = 0; rb < 4; ++rb)
            #pragma unroll
            for (int cb = 0; cb < 4; ++cb)
                acc[rb][cb] = __builtin_amdgcn_mfma_f32_16x16x32_bf16(
                    A[rb], A[cb], acc[rb][cb], 0, 0, 0);

        if (s + 2 < NK) {
            __builtin_amdgcn_sched_barrier(0);   // ds_reads consumed before reuse
            dma(s + 2, s & 1);
        }
    }

    // ---- S: per-wave partials -> workspace [bid][w][64] (stage2 sums) ----
    #pragma unroll
    for (int rb = 0; rb < 4; ++rb) {
        float v = csum[rb];
        v += __shfl_xor(v, 16, 64);
        v += __shfl_xor(v, 32, 64);
        if (lane < 16)
            S[((size_t)bid * 4 + w) * 64 + rb * 16 + lane] = v;
    }

    // ---- P: stash 4 partial Grams in reused LDS, merge after one barrier.
    //      D layout col=lane&15, row=(lane>>4)*4+reg (symmetric: swap-safe).
    float* st = &lds[0][0][0];            // 16384 floats; region w*4096.. is
    const int prow = (lane >> 4) << 2;    // this wave's own staging memory
    const int pcol = lane & 15;
    #pragma unroll
    for (int rb = 0; rb < 4; ++rb)
        #pragma unroll
        for (int cb = 0; cb < 4; ++cb)
            #pragma unroll
            for (int reg = 0; reg < 4; ++reg)
                st[w * 4096 + (rb * 16 + prow + reg) * 64 + cb * 16 + pcol]
                    = acc[rb][cb][reg];
    __syncthreads();

    float* Pc = P + ((size_t)bid << 12);
    for (int i = tid; i < 4096; i += 256)
        Pc[i] = (st[i] + st[4096 + i]) + (st[8192 + i] + st[12288 + i]);
}

// ---------------------------------------------------------------------------
// Stage 2: combine chunk (and per-wave S) partials -> corr -> threshold -> adj
// ---------------------------------------------------------------------------
__global__ __launch_bounds__(256) void corr_stage2(
    const float* __restrict__ P, const float* __restrict__ S,
    float* __restrict__ adj, int split)
{
    const int idx = blockIdx.x * 256 + threadIdx.x;   // < 128*4096
    const int b  = idx >> 12;
    const int nm = idx & 4095;
    const int n  = nm >> 6;
    const int m  = nm & 63;

    float G = 0.f, Gnn = 0.f, Gmm = 0.f, Sn = 0.f, Sm = 0.f;
    for (int c = 0; c < split; ++c) {
        const int bc = b * split + c;
        const float* Pc = P + ((size_t)bc << 12);
        G   += Pc[nm];
        Gnn += Pc[n * 65];
        Gmm += Pc[m * 65];
        #pragma unroll
        for (int w = 0; w < 4; ++w) {
            const float* Sc = S + ((size_t)bc * 4 + w) * 64;
            Sn += Sc[n];
            Sm += Sc[m];
        }
    }
    const float invT = 1.0f / (float)T_;
    const float cov  = G   - Sn * Sm * invT;
    const float vn   = Gnn - Sn * Sn * invT;
    const float vm   = Gmm - Sm * Sm * invT;
    const float den  = sqrtf(vn) * sqrtf(vm) + EPSF;
    float corr = cov / den;
    if (n == m) corr = 0.f;
    adj[idx] = (fabsf(corr) >= THRF) ? corr : 0.f;
}

// ---------------------------------------------------------------------------
extern "C" void kernel_launch(void* const* d_in, const int* in_sizes, int n_in,
                              void* d_out, int out_size, void* d_ws, size_t ws_size,
                              hipStream_t stream)
{
    const float* x   = (const float*)d_in[0];
    float* out   = (float*)d_out;
    float* adj   = out;                                  // 128*64*64
    float* out_x = out + (size_t)B_ * NCH * NCH;         // passthrough x

    // split=4 -> 512 blocks = 256 CU x 2 (64 KB LDS -> 2 blocks/CU).
    // Per-wave t-range Tc/4 = 1920 divisible by 32 ✓.
    int split = 4;
    while (split > 1 &&
           (size_t)B_ * split * (4096 + 4 * 64) * sizeof(float) > ws_size)
        split >>= 1;

    float* P = (float*)d_ws;
    float* S = P + (size_t)B_ * split * 4096;
    const int Tc = T_ / split;

    corr_stage1<<<dim3(B_ * split), dim3(256), 0, stream>>>(x, out_x, P, S, split, Tc);
    corr_stage2<<<dim3((B_ * 4096) / 256), dim3(256), 0, stream>>>(P, S, adj, split);
}

// Round 11
// 443.479 us; speedup vs baseline: 1.3309x; 1.3309x over previous
//
#include <hip/hip_runtime.h>
#include <hip/hip_bf16.h>
#include <cstdint>
#include <cstddef>

#define B_   128
#define NCH  64
#define T_   30720
#define EPSF 1e-12f
#define THRF 0.5f

typedef float  f32x4 __attribute__((ext_vector_type(4)));
typedef short  s16x8 __attribute__((ext_vector_type(8)));
typedef unsigned short u16;

#define AS1 __attribute__((address_space(1)))
#define AS3 __attribute__((address_space(3)))

static __device__ __forceinline__ short bf16s(float f) {
    return (short)__builtin_bit_cast(u16, __float2bfloat16(f));
}

// ---------------------------------------------------------------------------
// Stage 1: DMA-staged streaming Gram + fused copy. R9 structure EXCEPT the
// copy-out uses PLAIN (cached) stores instead of nontemporal (single-change
// A/B). Theory: NT stores bypass L2 write-combining -> fine-grained UC
// writes to HBM (R3/R10 PMC: WRITE_SIZE 1.33-1.4x ideal) + full-HBM-latency
// store retirement. Cached stores aggregate dirty lines in L2 and write
// back in controller-friendly bursts (how fillBuffer sustains 6.8 TB/s).
// Everything else identical to R9 (verified, absmax 0):
//   - [2][64ch][128t] f32 LDS, global_load_lds dwordx4 staging
//   - counted vmcnt(8) + raw s_barrier per tile
//   - copy-out: ds_read -> contiguous 512B/instr stores + fp32 csums
//   - Gram: cvt f32->bf16, 16 MFMA/wave, full 64x64 (symmetric)
//   - LDS swizzle via pre-swizzled DMA global source
// ---------------------------------------------------------------------------
__global__ __launch_bounds__(256) void corr_stage1(
    const float* __restrict__ x, float* __restrict__ out_x,
    float* __restrict__ P, float* __restrict__ S,
    int split, int Tc)
{
    __shared__ __align__(16) float lds[2][NCH * 128];   // 2 x 32 KB

    const int tid  = threadIdx.x;
    const int lane = tid & 63;
    const int w    = tid >> 6;          // wave 0..3

    const int bid = blockIdx.x;
    const int b   = bid / split;
    const int c   = bid - b * split;

    const size_t base = (size_t)b * ((size_t)NCH * T_) + (size_t)c * Tc;
    const float* xw = x + base;
    float*       ow = out_x + base;

    const int NT = Tc >> 7;             // 128-t tiles per chunk

    // DMA / copy lane mapping: instr k (0..31) covers rows 2k, 2k+1;
    // lane: row = 2k + (lane>>5), granule slot = lane&31 (16 B granules).
    const int sg = lane & 31;
    const int hi = lane >> 5;

    // fragment mapping
    const int fr = lane & 15;           // fragment row within 16-ch block
    const int g8 = lane >> 4;           // k-subgroup 0..3
    const int fs = fr & 7;              // row swizzle

    f32x4 acc[4];
    #pragma unroll
    for (int cb = 0; cb < 4; ++cb) acc[cb] = (f32x4)(0.f);
    float csum[8];
    #pragma unroll
    for (int kk = 0; kk < 8; ++kk) csum[kk] = 0.f;

    auto dma = [&](int tile, int buf) {
        #pragma unroll
        for (int kk = 0; kk < 8; ++kk) {
            const int k  = w * 8 + kk;
            const int ch = 2 * k + hi;
            const int gg = sg ^ (ch & 7);               // pre-swizzled source
            const float* src = xw + (size_t)ch * T_ + (size_t)(tile * 128 + gg * 4);
            float* dst = &lds[buf][k * 256];            // wave-uniform, linear
            __builtin_amdgcn_global_load_lds((const AS1 void*)src,
                                             (AS3 void*)dst, 16, 0, 0);
        }
    };

    dma(0, 0);
    asm volatile("s_waitcnt vmcnt(0)" ::: "memory");
    __builtin_amdgcn_s_barrier();
    __builtin_amdgcn_sched_barrier(0);

    for (int t = 0; t < NT; ++t) {
        const int cur = t & 1;
        if (t + 1 < NT) dma(t + 1, cur ^ 1);

        // ---- copy-out: contiguous 512B/instr cached stores + sums ----
        #pragma unroll
        for (int kk = 0; kk < 8; ++kk) {
            const int k   = w * 8 + kk;
            const int row = 2 * k + hi;
            const f32x4 v = *reinterpret_cast<const f32x4*>(
                &lds[cur][row * 128 + ((sg ^ (row & 7)) << 2)]);
            float* q = ow + (size_t)row * T_ + (size_t)(t * 128 + sg * 4);
            *reinterpret_cast<f32x4*>(q) = v;           // PLAIN store (A/B vs NT)
            csum[kk] += ((v.x + v.y) + (v.z + v.w));
        }

        // ---- Gram: 4 K-steps of 32 ----
        #pragma unroll
        for (int ks = 0; ks < 4; ++ks) {
            const int g0 = ks * 8 + g8 * 2;
            const f32x4 alo = *reinterpret_cast<const f32x4*>(
                &lds[cur][(w * 16 + fr) * 128 + ((g0 ^ fs) << 2)]);
            const f32x4 ahi = *reinterpret_cast<const f32x4*>(
                &lds[cur][(w * 16 + fr) * 128 + (((g0 + 1) ^ fs) << 2)]);
            s16x8 Af;
            Af[0] = bf16s(alo.x); Af[1] = bf16s(alo.y);
            Af[2] = bf16s(alo.z); Af[3] = bf16s(alo.w);
            Af[4] = bf16s(ahi.x); Af[5] = bf16s(ahi.y);
            Af[6] = bf16s(ahi.z); Af[7] = bf16s(ahi.w);
            #pragma unroll
            for (int cb = 0; cb < 4; ++cb) {
                s16x8 Bf;
                if (cb == w) {
                    Bf = Af;
                } else {
                    const f32x4 blo = *reinterpret_cast<const f32x4*>(
                        &lds[cur][(cb * 16 + fr) * 128 + ((g0 ^ fs) << 2)]);
                    const f32x4 bhi = *reinterpret_cast<const f32x4*>(
                        &lds[cur][(cb * 16 + fr) * 128 + (((g0 + 1) ^ fs) << 2)]);
                    Bf[0] = bf16s(blo.x); Bf[1] = bf16s(blo.y);
                    Bf[2] = bf16s(blo.z); Bf[3] = bf16s(blo.w);
                    Bf[4] = bf16s(bhi.x); Bf[5] = bf16s(bhi.y);
                    Bf[6] = bf16s(bhi.z); Bf[7] = bf16s(bhi.w);
                }
                acc[cb] = __builtin_amdgcn_mfma_f32_16x16x32_bf16(Af, Bf, acc[cb], 0, 0, 0);
            }
        }

        // counted wait: own DMA(t+1) retired; this tile's stores (now L2-
        // retiring, fast) may remain in flight across the barrier.
        asm volatile("s_waitcnt vmcnt(8)" ::: "memory");
        __builtin_amdgcn_s_barrier();
        __builtin_amdgcn_sched_barrier(0);
    }

    // ---- S: reduce csum across the 32 lanes sharing (w,kk,hi) ----
    #pragma unroll
    for (int kk = 0; kk < 8; ++kk) {
        float v = csum[kk];
        v += __shfl_xor(v, 1,  64);
        v += __shfl_xor(v, 2,  64);
        v += __shfl_xor(v, 4,  64);
        v += __shfl_xor(v, 8,  64);
        v += __shfl_xor(v, 16, 64);
        if ((lane & 31) == 0) {
            const int row = 2 * (w * 8 + kk) + hi;
            S[(size_t)bid * NCH + row] = v;
        }
    }

    // ---- P: wave w owns rows w*16..w*16+15, all 4 col blocks.
    //      D layout col=lane&15, row=(lane>>4)*4+reg (transpose-safe: symmetric).
    float* Pc = P + ((size_t)bid << 12);
    const int prow = (lane >> 4) << 2;
    const int pcol = lane & 15;
    #pragma unroll
    for (int cb = 0; cb < 4; ++cb)
        #pragma unroll
        for (int reg = 0; reg < 4; ++reg)
            Pc[(w * 16 + prow + reg) * 64 + cb * 16 + pcol] = acc[cb][reg];
}

// ---------------------------------------------------------------------------
// Stage 2: combine chunk partials -> corr -> threshold -> adj
// ---------------------------------------------------------------------------
__global__ __launch_bounds__(256) void corr_stage2(
    const float* __restrict__ P, const float* __restrict__ S,
    float* __restrict__ adj, int split)
{
    const int idx = blockIdx.x * 256 + threadIdx.x;   // < 128*4096
    const int b  = idx >> 12;
    const int nm = idx & 4095;
    const int n  = nm >> 6;
    const int m  = nm & 63;

    float G = 0.f, Gnn = 0.f, Gmm = 0.f, Sn = 0.f, Sm = 0.f;
    for (int c = 0; c < split; ++c) {
        const float* Pc = P + ((size_t)(b * split + c) << 12);
        const float* Sc = S + (size_t)(b * split + c) * NCH;
        G   += Pc[nm];
        Gnn += Pc[n * 65];
        Gmm += Pc[m * 65];
        Sn  += Sc[n];
        Sm  += Sc[m];
    }
    const float invT = 1.0f / (float)T_;
    const float cov  = G   - Sn * Sm * invT;
    const float vn   = Gnn - Sn * Sn * invT;
    const float vm   = Gmm - Sm * Sm * invT;
    const float den  = sqrtf(vn) * sqrtf(vm) + EPSF;
    float corr = cov / den;
    if (n == m) corr = 0.f;
    adj[idx] = (fabsf(corr) >= THRF) ? corr : 0.f;
}

// ---------------------------------------------------------------------------
extern "C" void kernel_launch(void* const* d_in, const int* in_sizes, int n_in,
                              void* d_out, int out_size, void* d_ws, size_t ws_size,
                              hipStream_t stream)
{
    const float* x   = (const float*)d_in[0];
    float* out   = (float*)d_out;
    float* adj   = out;                                  // 128*64*64
    float* out_x = out + (size_t)B_ * NCH * NCH;         // passthrough x

    // split=4 -> 512 blocks = 256 CU x 2 exactly (64 KB LDS -> 2 blocks/CU).
    int split = 4;
    while (split > 1 &&
           (size_t)B_ * split * (4096 + NCH) * sizeof(float) > ws_size)
        split >>= 1;

    float* P = (float*)d_ws;
    float* S = P + (size_t)B_ * split * 4096;
    const int Tc = T_ / split;

    corr_stage1<<<dim3(B_ * split), dim3(256), 0, stream>>>(x, out_x, P, S, split, Tc);
    corr_stage2<<<dim3((B_ * 4096) / 256), dim3(256), 0, stream>>>(P, S, adj, split);
}

// Round 12
// 433.192 us; speedup vs baseline: 1.3625x; 1.0237x over previous
//
#include <hip/hip_runtime.h>
#include <hip/hip_bf16.h>
#include <cstdint>
#include <cstddef>

#define B_   128
#define NCH  64
#define T_   30720
#define EPSF 1e-12f
#define THRF 0.5f

typedef float  f32x4 __attribute__((ext_vector_type(4)));
typedef short  s16x8 __attribute__((ext_vector_type(8)));
typedef unsigned short u16;

#define AS1 __attribute__((address_space(1)))
#define AS3 __attribute__((address_space(3)))

static __device__ __forceinline__ short bf16s(float f) {
    return (short)__builtin_bit_cast(u16, __float2bfloat16(f));
}

// ---------------------------------------------------------------------------
// Stage 1: producer/consumer wave-specialized DMA pipeline.
// 512 threads = 8 waves; same 2x32KB LDS + grid as R11 -> 16 waves/CU (2x TLP
// at constant barrier-per-byte; R11 model showed ~50% all-pipes-idle at 8
// waves/CU). Per 128-t tile:
//   all 8 waves:  4x global_load_lds dwordx4 each for tile t+1 (64 KB of
//                 reads in flight per CU).
//   waves 0-3:    COPY tile t: 8x {ds_read_b128 -> cached 512B store} +
//                 fp32 row sums. vmcnt(8) at bottom (stores stay in flight,
//                 own DMAs retired -- in-order queue [DMA 4, ST 8]).
//   waves 4-7:    GRAM tile t: quadrant (qr,qc) of 64x64; per K-step of 32:
//                 8 ds_read_b128 (2 A-blocks + 2 B-blocks), cvt->bf16,
//                 4 MFMA. No stores -> vmcnt(0) covered by own compute.
//   one s_barrier per tile; buffer flip.
// Epilogue: Gram waves write their exclusive quadrant to P directly (no
// LDS merge, no extra barrier); copy waves shfl-reduce S (complete sums).
// LDS swizzle: granule^(row&7) via pre-swizzled DMA source (dest linear).
// bf16 Gram (symmetric, transpose-immune); corr err ~4e-3 << 0.108 thresh.
// ---------------------------------------------------------------------------
__global__ __launch_bounds__(512) void corr_stage1(
    const float* __restrict__ x, float* __restrict__ out_x,
    float* __restrict__ P, float* __restrict__ S,
    int split, int Tc)
{
    __shared__ __align__(16) float lds[2][NCH * 128];   // 2 x 32 KB

    const int tid  = threadIdx.x;
    const int lane = tid & 63;
    const int w    = tid >> 6;          // wave 0..7

    const int bid = blockIdx.x;
    const int b   = bid / split;
    const int c   = bid - b * split;

    const size_t base = (size_t)b * ((size_t)NCH * T_) + (size_t)c * Tc;
    const float* xw = x + base;
    float*       ow = out_x + base;

    const int NT = Tc >> 7;             // 128-t tiles per chunk

    const int hi = lane >> 5;           // row half within a DMA instr
    const int sg = lane & 31;           // 16B granule slot

    // each wave issues 4 DMA instrs: instr j = w*4+i covers rows 2j,2j+1
    auto dma = [&](int tile, int buf) {
        #pragma unroll
        for (int i = 0; i < 4; ++i) {
            const int j  = w * 4 + i;
            const int ch = 2 * j + hi;
            const int gg = sg ^ (ch & 7);               // pre-swizzled source
            const float* src = xw + (size_t)ch * T_ + (size_t)(tile * 128 + gg * 4);
            float* dst = &lds[buf][j * 256];            // wave-uniform, linear
            __builtin_amdgcn_global_load_lds((const AS1 void*)src,
                                             (AS3 void*)dst, 16, 0, 0);
        }
    };

    dma(0, 0);
    asm volatile("s_waitcnt vmcnt(0)" ::: "memory");
    __builtin_amdgcn_s_barrier();
    __builtin_amdgcn_sched_barrier(0);

    if (w < 4) {
        // ================= COPY + S waves =================
        float csum[8];
        #pragma unroll
        for (int kk = 0; kk < 8; ++kk) csum[kk] = 0.f;

        for (int t = 0; t < NT; ++t) {
            const int cur = t & 1;
            if (t + 1 < NT) dma(t + 1, cur ^ 1);

            #pragma unroll
            for (int kk = 0; kk < 8; ++kk) {
                const int row = 16 * w + 2 * kk + hi;
                const f32x4 v = *reinterpret_cast<const f32x4*>(
                    &lds[cur][row * 128 + ((sg ^ (row & 7)) << 2)]);
                *reinterpret_cast<f32x4*>(
                    ow + (size_t)row * T_ + (size_t)(t * 128 + sg * 4)) = v;
                csum[kk] += ((v.x + v.y) + (v.z + v.w));
            }

            asm volatile("s_waitcnt vmcnt(8)" ::: "memory");
            __builtin_amdgcn_s_barrier();
            __builtin_amdgcn_sched_barrier(0);
        }

        #pragma unroll
        for (int kk = 0; kk < 8; ++kk) {
            float v = csum[kk];
            v += __shfl_xor(v, 1,  64);
            v += __shfl_xor(v, 2,  64);
            v += __shfl_xor(v, 4,  64);
            v += __shfl_xor(v, 8,  64);
            v += __shfl_xor(v, 16, 64);
            if ((lane & 31) == 0)
                S[(size_t)bid * NCH + 16 * w + 2 * kk + hi] = v;
        }
    } else {
        // ================= GRAM waves =================
        const int q  = w - 4;
        const int qr = q >> 1, qc = q & 1;   // 32x32 quadrant coords
        const int fr = lane & 15;
        const int g8 = lane >> 4;
        const int fs = fr & 7;

        f32x4 acc[2][2];
        #pragma unroll
        for (int rb = 0; rb < 2; ++rb)
            #pragma unroll
            for (int cb = 0; cb < 2; ++cb) acc[rb][cb] = (f32x4)(0.f);

        for (int t = 0; t < NT; ++t) {
            const int cur = t & 1;
            if (t + 1 < NT) dma(t + 1, cur ^ 1);

            #pragma unroll
            for (int ks = 0; ks < 4; ++ks) {
                const int gl = (ks * 8 + 2 * g8) ^ fs;
                const int gh = (ks * 8 + 2 * g8 + 1) ^ fs;
                s16x8 frag[4];
                #pragma unroll
                for (int e = 0; e < 4; ++e) {
                    const int blk = (e < 2) ? (2 * qr + e) : (2 * qc + (e - 2));
                    const int ro  = (blk * 16 + fr) * 128;
                    const f32x4 lo = *reinterpret_cast<const f32x4*>(
                        &lds[cur][ro + (gl << 2)]);
                    const f32x4 hv = *reinterpret_cast<const f32x4*>(
                        &lds[cur][ro + (gh << 2)]);
                    frag[e][0] = bf16s(lo.x); frag[e][1] = bf16s(lo.y);
                    frag[e][2] = bf16s(lo.z); frag[e][3] = bf16s(lo.w);
                    frag[e][4] = bf16s(hv.x); frag[e][5] = bf16s(hv.y);
                    frag[e][6] = bf16s(hv.z); frag[e][7] = bf16s(hv.w);
                }
                #pragma unroll
                for (int rb = 0; rb < 2; ++rb)
                    #pragma unroll
                    for (int cb = 0; cb < 2; ++cb)
                        acc[rb][cb] = __builtin_amdgcn_mfma_f32_16x16x32_bf16(
                            frag[rb], frag[2 + cb], acc[rb][cb], 0, 0, 0);
            }

            asm volatile("s_waitcnt vmcnt(0)" ::: "memory");
            __builtin_amdgcn_s_barrier();
            __builtin_amdgcn_sched_barrier(0);
        }

        // ---- P: exclusive quadrant write; D layout col=lane&15,
        //      row=(lane>>4)*4+reg (symmetric: transpose-safe) ----
        float* Pc = P + ((size_t)bid << 12);
        const int prow = (lane >> 4) << 2;
        const int pcol = lane & 15;
        #pragma unroll
        for (int rb = 0; rb < 2; ++rb)
            #pragma unroll
            for (int cb = 0; cb < 2; ++cb)
                #pragma unroll
                for (int reg = 0; reg < 4; ++reg)
                    Pc[((2 * qr + rb) * 16 + prow + reg) * 64
                       + (2 * qc + cb) * 16 + pcol] = acc[rb][cb][reg];
    }
}

// ---------------------------------------------------------------------------
// Stage 2: combine chunk partials -> corr -> threshold -> adj
// ---------------------------------------------------------------------------
__global__ __launch_bounds__(256) void corr_stage2(
    const float* __restrict__ P, const float* __restrict__ S,
    float* __restrict__ adj, int split)
{
    const int idx = blockIdx.x * 256 + threadIdx.x;   // < 128*4096
    const int b  = idx >> 12;
    const int nm = idx & 4095;
    const int n  = nm >> 6;
    const int m  = nm & 63;

    float G = 0.f, Gnn = 0.f, Gmm = 0.f, Sn = 0.f, Sm = 0.f;
    for (int c = 0; c < split; ++c) {
        const float* Pc = P + ((size_t)(b * split + c) << 12);
        const float* Sc = S + (size_t)(b * split + c) * NCH;
        G   += Pc[nm];
        Gnn += Pc[n * 65];
        Gmm += Pc[m * 65];
        Sn  += Sc[n];
        Sm  += Sc[m];
    }
    const float invT = 1.0f / (float)T_;
    const float cov  = G   - Sn * Sm * invT;
    const float vn   = Gnn - Sn * Sn * invT;
    const float vm   = Gmm - Sm * Sm * invT;
    const float den  = sqrtf(vn) * sqrtf(vm) + EPSF;
    float corr = cov / den;
    if (n == m) corr = 0.f;
    adj[idx] = (fabsf(corr) >= THRF) ? corr : 0.f;
}

// ---------------------------------------------------------------------------
extern "C" void kernel_launch(void* const* d_in, const int* in_sizes, int n_in,
                              void* d_out, int out_size, void* d_ws, size_t ws_size,
                              hipStream_t stream)
{
    const float* x   = (const float*)d_in[0];
    float* out   = (float*)d_out;
    float* adj   = out;                                  // 128*64*64
    float* out_x = out + (size_t)B_ * NCH * NCH;         // passthrough x

    // split=4 -> 512 blocks of 512 thr = 2 blocks/CU (128 KB LDS, 16 waves).
    int split = 4;
    while (split > 1 &&
           (size_t)B_ * split * (4096 + NCH) * sizeof(float) > ws_size)
        split >>= 1;

    float* P = (float*)d_ws;
    float* S = P + (size_t)B_ * split * 4096;
    const int Tc = T_ / split;

    corr_stage1<<<dim3(B_ * split), dim3(512), 0, stream>>>(x, out_x, P, S, split, Tc);
    corr_stage2<<<dim3((B_ * 4096) / 256), dim3(256), 0, stream>>>(P, S, adj, split);
}

// Round 13
// 428.478 us; speedup vs baseline: 1.3775x; 1.0110x over previous
//
#include <hip/hip_runtime.h>
#include <hip/hip_bf16.h>
#include <cstdint>
#include <cstddef>

#define B_   128
#define NCH  64
#define T_   30720
#define TW   256          // tile t-width: 1 KB contiguous per channel per tile
#define EPSF 1e-12f
#define THRF 0.5f

typedef float  f32x4 __attribute__((ext_vector_type(4)));
typedef short  s16x8 __attribute__((ext_vector_type(8)));
typedef unsigned short u16;

#define AS1 __attribute__((address_space(1)))
#define AS3 __attribute__((address_space(3)))

static __device__ __forceinline__ short bf16s(float f) {
    return (short)__builtin_bit_cast(u16, __float2bfloat16(f));
}

// ---------------------------------------------------------------------------
// Stage 1: DMA-staged streaming Gram + fused copy, 1 KB-chunk edition.
// Theory: R8-R12 (433-453 us, all pipes idle) are DRAM row-activate limited:
// 512 B chunks = 1 activate per 512 B at a ~tRC-capped rate. This doubles
// the contiguous chunk: tile [64ch][256t] f32 (64 KB), double-buffered =
// 128 KB dynamic LDS, 1024 thr / 16 waves, split=2 -> 256 blocks = 1/CU.
//   all 16 waves: 4 DMA instrs each, one FULL 1 KB row per instr.
//   waves 0-7  COPY: 8 rows each: ds_read row -> linear 1 KB cached store +
//              fp32 row sums; vmcnt(8) (stores fly across barrier).
//   waves 8-15 GRAM: quadrant q=(w-8)&3, K-parity par=(w-8)>>2; per owned
//              K-step (4 of 8): 8 ds_read_b128, cvt->bf16, 4 MFMA; vmcnt(0).
//   one s_barrier per tile (equal count in both branches); buffer flip.
// Epilogue: odd-parity waves stash acc in buf0; __syncthreads; even-parity
// waves write (own acc + stash) to their exclusive P quadrant; copy waves
// write S. LDS swizzle: granule^(row&7) via pre-swizzled DMA source.
// bf16 Gram (symmetric, transpose-immune); corr err ~4e-3 << 0.108 thresh.
// ---------------------------------------------------------------------------
__global__ __launch_bounds__(1024) void corr_stage1(
    const float* __restrict__ x, float* __restrict__ out_x,
    float* __restrict__ P, float* __restrict__ S,
    int split, int Tc)
{
    extern __shared__ __align__(16) float lds[];   // [2][64][TW] = 128 KB

    const int tid  = threadIdx.x;
    const int lane = tid & 63;
    const int w    = tid >> 6;          // wave 0..15

    const int bid = blockIdx.x;
    const int b   = bid / split;
    const int c   = bid - b * split;

    const size_t base = (size_t)b * ((size_t)NCH * T_) + (size_t)c * Tc;
    const float* xw = x + base;
    float*       ow = out_x + base;

    const int NT  = Tc / TW;            // tiles per chunk (=60 at split=2)
    const int BUF = NCH * TW;           // floats per buffer (16384)

    auto dma = [&](int tile, int buf) {
        #pragma unroll
        for (int i = 0; i < 4; ++i) {
            const int r  = w * 4 + i;
            const int gg = lane ^ (r & 7);            // pre-swizzled source
            const float* src = xw + (size_t)r * T_ + (size_t)(tile * TW + gg * 4);
            float* dst = &lds[buf * BUF + r * TW];    // wave-uniform, linear
            __builtin_amdgcn_global_load_lds((const AS1 void*)src,
                                             (AS3 void*)dst, 16, 0, 0);
        }
    };

    dma(0, 0);
    asm volatile("s_waitcnt vmcnt(0)" ::: "memory");
    __builtin_amdgcn_s_barrier();
    __builtin_amdgcn_sched_barrier(0);

    if (w < 8) {
        // ============ COPY + S waves (rows w*8 .. w*8+7) ============
        float csum[8];
        #pragma unroll
        for (int i = 0; i < 8; ++i) csum[i] = 0.f;

        for (int t = 0; t < NT; ++t) {
            const int cur = t & 1;
            if (t + 1 < NT) dma(t + 1, cur ^ 1);

            #pragma unroll
            for (int i = 0; i < 8; ++i) {
                const int row  = w * 8 + i;
                const int slot = lane ^ (row & 7);    // undo source swizzle
                const f32x4 v = *reinterpret_cast<const f32x4*>(
                    &lds[cur * BUF + row * TW + slot * 4]);
                *reinterpret_cast<f32x4*>(
                    ow + (size_t)row * T_ + (size_t)(t * TW + lane * 4)) = v;
                csum[i] += ((v.x + v.y) + (v.z + v.w));
            }

            asm volatile("s_waitcnt vmcnt(8)" ::: "memory");
            __builtin_amdgcn_s_barrier();
            __builtin_amdgcn_sched_barrier(0);
        }

        __syncthreads();   // match Gram waves' epilogue barrier

        #pragma unroll
        for (int i = 0; i < 8; ++i) {
            float v = csum[i];
            v += __shfl_xor(v, 1,  64);
            v += __shfl_xor(v, 2,  64);
            v += __shfl_xor(v, 4,  64);
            v += __shfl_xor(v, 8,  64);
            v += __shfl_xor(v, 16, 64);
            v += __shfl_xor(v, 32, 64);
            if (lane == 0)
                S[(size_t)bid * NCH + w * 8 + i] = v;
        }
    } else {
        // ============ GRAM waves ============
        const int g   = w - 8;
        const int q   = g & 3;
        const int par = g >> 2;
        const int qr  = q >> 1, qc = q & 1;
        const int fr  = lane & 15;
        const int g8  = lane >> 4;
        const int fs  = fr & 7;

        f32x4 acc[2][2];
        #pragma unroll
        for (int rb = 0; rb < 2; ++rb)
            #pragma unroll
            for (int cb = 0; cb < 2; ++cb) acc[rb][cb] = (f32x4)(0.f);

        for (int t = 0; t < NT; ++t) {
            const int cur = t & 1;
            if (t + 1 < NT) dma(t + 1, cur ^ 1);

            #pragma unroll
            for (int kk = 0; kk < 4; ++kk) {
                const int ks = par + 2 * kk;
                const int gl = (ks * 8 + 2 * g8) ^ fs;
                const int gh = (ks * 8 + 2 * g8 + 1) ^ fs;
                s16x8 frag[4];
                #pragma unroll
                for (int e = 0; e < 4; ++e) {
                    const int blk = (e < 2) ? (2 * qr + e) : (2 * qc + (e - 2));
                    const int ro  = cur * BUF + (blk * 16 + fr) * TW;
                    const f32x4 lo = *reinterpret_cast<const f32x4*>(&lds[ro + gl * 4]);
                    const f32x4 hv = *reinterpret_cast<const f32x4*>(&lds[ro + gh * 4]);
                    frag[e][0] = bf16s(lo.x); frag[e][1] = bf16s(lo.y);
                    frag[e][2] = bf16s(lo.z); frag[e][3] = bf16s(lo.w);
                    frag[e][4] = bf16s(hv.x); frag[e][5] = bf16s(hv.y);
                    frag[e][6] = bf16s(hv.z); frag[e][7] = bf16s(hv.w);
                }
                #pragma unroll
                for (int rb = 0; rb < 2; ++rb)
                    #pragma unroll
                    for (int cb = 0; cb < 2; ++cb)
                        acc[rb][cb] = __builtin_amdgcn_mfma_f32_16x16x32_bf16(
                            frag[rb], frag[2 + cb], acc[rb][cb], 0, 0, 0);
            }

            asm volatile("s_waitcnt vmcnt(0)" ::: "memory");
            __builtin_amdgcn_s_barrier();
            __builtin_amdgcn_sched_barrier(0);
        }

        // odd-parity waves stash acc into buf0 rows 0..15 (no longer read)
        if (par == 1) {
            #pragma unroll
            for (int rb = 0; rb < 2; ++rb)
                #pragma unroll
                for (int cb = 0; cb < 2; ++cb)
                    #pragma unroll
                    for (int reg = 0; reg < 4; ++reg)
                        lds[q * 1024 + lane * 16 + rb * 8 + cb * 4 + reg]
                            = acc[rb][cb][reg];
        }

        __syncthreads();

        if (par == 0) {
            float* Pc = P + ((size_t)bid << 12);
            const int prow = (lane >> 4) << 2;
            const int pcol = lane & 15;
            #pragma unroll
            for (int rb = 0; rb < 2; ++rb)
                #pragma unroll
                for (int cb = 0; cb < 2; ++cb)
                    #pragma unroll
                    for (int reg = 0; reg < 4; ++reg)
                        Pc[((2 * qr + rb) * 16 + prow + reg) * 64
                           + (2 * qc + cb) * 16 + pcol]
                            = acc[rb][cb][reg]
                            + lds[q * 1024 + lane * 16 + rb * 8 + cb * 4 + reg];
        }
    }
}

// ---------------------------------------------------------------------------
// Stage 2: combine chunk partials -> corr -> threshold -> adj
// ---------------------------------------------------------------------------
__global__ __launch_bounds__(256) void corr_stage2(
    const float* __restrict__ P, const float* __restrict__ S,
    float* __restrict__ adj, int split)
{
    const int idx = blockIdx.x * 256 + threadIdx.x;   // < 128*4096
    const int b  = idx >> 12;
    const int nm = idx & 4095;
    const int n  = nm >> 6;
    const int m  = nm & 63;

    float G = 0.f, Gnn = 0.f, Gmm = 0.f, Sn = 0.f, Sm = 0.f;
    for (int c = 0; c < split; ++c) {
        const float* Pc = P + ((size_t)(b * split + c) << 12);
        const float* Sc = S + (size_t)(b * split + c) * NCH;
        G   += Pc[nm];
        Gnn += Pc[n * 65];
        Gmm += Pc[m * 65];
        Sn  += Sc[n];
        Sm  += Sc[m];
    }
    const float invT = 1.0f / (float)T_;
    const float cov  = G   - Sn * Sm * invT;
    const float vn   = Gnn - Sn * Sn * invT;
    const float vm   = Gmm - Sm * Sm * invT;
    const float den  = sqrtf(vn) * sqrtf(vm) + EPSF;
    float corr = cov / den;
    if (n == m) corr = 0.f;
    adj[idx] = (fabsf(corr) >= THRF) ? corr : 0.f;
}

// ---------------------------------------------------------------------------
extern "C" void kernel_launch(void* const* d_in, const int* in_sizes, int n_in,
                              void* d_out, int out_size, void* d_ws, size_t ws_size,
                              hipStream_t stream)
{
    const float* x   = (const float*)d_in[0];
    float* out   = (float*)d_out;
    float* adj   = out;                                  // 128*64*64
    float* out_x = out + (size_t)B_ * NCH * NCH;         // passthrough x

    // split=2 -> 256 blocks of 1024 thr = 1 block/CU (128 KB dynamic LDS).
    const int split = 2;
    float* P = (float*)d_ws;
    float* S = P + (size_t)B_ * split * 4096;
    const int Tc = T_ / split;                           // 15360, NT=60

    corr_stage1<<<dim3(B_ * split), dim3(1024), 131072, stream>>>(
        x, out_x, P, S, split, Tc);
    corr_stage2<<<dim3((B_ * 4096) / 256), dim3(256), 0, stream>>>(P, S, adj, split);
}